// Round 11
// baseline (269.313 us; speedup 1.0000x reference)
//
#include <hip/hip_runtime.h>
#include <hip/hip_bf16.h>
#include <math.h>

// Problem constants
#define BB 32
#define SS 2048
#define HH 1024
#define DD 1024
#define HD 2048
#define NSPLIT 32   // 64-row chunks per batch (max)
#define KSPLIT 16   // K-splits for out GEMM
#define NEG_BIG -1e10f

__device__ __forceinline__ float wave_reduce_sum(float v) {
#pragma unroll
    for (int off = 32; off > 0; off >>= 1) v += __shfl_xor(v, off, 64);
    return v;
}

__device__ __forceinline__ float dot4(float4 a, float4 b) {
    return a.x * b.x + a.y * b.y + a.z * b.z + a.w * b.w;
}

// ---------------- K1: x = hidden @ W1^T; also zero fan-in counters ----------------
// grid 256, block 256. One wave per output d-row; hidden read direct (L2-hot).
__global__ __launch_bounds__(256) void k1_gemv_x(const float* __restrict__ hidden,
                                                 const float* __restrict__ W1,
                                                 float* __restrict__ x,
                                                 int* __restrict__ cnt) {
    if (blockIdx.x == 0 && threadIdx.x < 64) cnt[threadIdx.x] = 0;  // fan-in counters
    int tid = threadIdx.x;
    int w = tid >> 6, lane = tid & 63;
    int d = blockIdx.x * 4 + w;
    const float4* wp = (const float4*)(W1 + (size_t)d * HH);
    float4 w0 = wp[lane], w1 = wp[lane + 64], w2 = wp[lane + 128], w3 = wp[lane + 192];
    const float4* hp = (const float4*)hidden;
#pragma unroll 2
    for (int b = 0; b < BB; b += 2) {
        const float4* h0 = hp + b * 256;
        const float4* h1 = hp + (b + 1) * 256;
        float s0 = dot4(h0[lane], w0) + dot4(h0[lane + 64], w1) +
                   dot4(h0[lane + 128], w2) + dot4(h0[lane + 192], w3);
        float s1 = dot4(h1[lane], w0) + dot4(h1[lane + 64], w1) +
                   dot4(h1[lane + 128], w2) + dot4(h1[lane + 192], w3);
#pragma unroll
        for (int off = 32; off > 0; off >>= 1) {
            s0 += __shfl_xor(s0, off, 64);
            s1 += __shfl_xor(s1, off, 64);
        }
        if (lane == 0) {
            x[b * DD + d] = s0;
            x[(b + 1) * DD + d] = s1;
        }
    }
}

// ---------------- K2': fused scores + ctx partials + per-batch fan-in combine ----------------
// grid 512, block 512 (8 waves x 8 rows per 64-row chunk). The LAST block to
// finish a batch's chunks combines its partials -> ctx, Mb, Lb (no spinning).
__global__ __launch_bounds__(512) void k2_fused(const float* __restrict__ enc,
                                                const float* __restrict__ x,
                                                const int* __restrict__ src_lens,
                                                float* __restrict__ scores,
                                                float* __restrict__ ctxp,
                                                float* __restrict__ m_part,
                                                float* __restrict__ l_part,
                                                float* __restrict__ ctx,
                                                float* __restrict__ Mb,
                                                float* __restrict__ Lb,
                                                int* __restrict__ cnt) {
    int tid = threadIdx.x;
    int w = tid >> 6, lane = tid & 63;

    __shared__ int pfx[BB + 1];
    if (tid == 0) {
        int a = 0;
        pfx[0] = 0;
#pragma unroll
        for (int b = 0; b < BB; ++b) {
            a += (src_lens[b] + 63) >> 6;
            pfx[b + 1] = a;
        }
    }
    __shared__ float4 lctx[8][256];  // 32 KB
    __shared__ float lm[8], ll[8];
    __shared__ int lastflag;
    __shared__ float sM, sL;
    __syncthreads();
    int total = pfx[BB];

    for (int chunk = blockIdx.x; chunk < total; chunk += gridDim.x) {
        int b = 0;
        while (pfx[b + 1] <= chunk) ++b;  // uniform, <=32 iters
        int sp = chunk - pfx[b];
        int len = src_lens[b];
        int nb = (len + 63) >> 6;
        int srow = sp * 64 + w * 8;

        float m = NEG_BIG, l = 0.f;
        float4 a0 = {0, 0, 0, 0}, a1 = {0, 0, 0, 0}, a2 = {0, 0, 0, 0}, a3 = {0, 0, 0, 0};

        if (srow < len) {
            const float4* xp = (const float4*)(x + (size_t)b * DD);
            float4 x0 = xp[lane], x1 = xp[lane + 64], x2 = xp[lane + 128], x3 = xp[lane + 192];
            int rend = min(8, len - srow);
            const float* erow = enc + ((size_t)b * SS + srow) * DD;
            int r = 0;
            for (; r + 4 <= rend; r += 4) {
                const float4* pr0 = (const float4*)(erow + (size_t)(r + 0) * DD);
                const float4* pr1 = (const float4*)(erow + (size_t)(r + 1) * DD);
                const float4* pr2 = (const float4*)(erow + (size_t)(r + 2) * DD);
                const float4* pr3 = (const float4*)(erow + (size_t)(r + 3) * DD);
                float4 e00 = pr0[lane], e01 = pr0[lane + 64], e02 = pr0[lane + 128], e03 = pr0[lane + 192];
                float4 e10 = pr1[lane], e11 = pr1[lane + 64], e12 = pr1[lane + 128], e13 = pr1[lane + 192];
                float4 e20 = pr2[lane], e21 = pr2[lane + 64], e22 = pr2[lane + 128], e23 = pr2[lane + 192];
                float4 e30 = pr3[lane], e31 = pr3[lane + 64], e32 = pr3[lane + 128], e33 = pr3[lane + 192];
                float p0 = dot4(e00, x0) + dot4(e01, x1) + dot4(e02, x2) + dot4(e03, x3);
                float p1 = dot4(e10, x0) + dot4(e11, x1) + dot4(e12, x2) + dot4(e13, x3);
                float p2 = dot4(e20, x0) + dot4(e21, x1) + dot4(e22, x2) + dot4(e23, x3);
                float p3 = dot4(e30, x0) + dot4(e31, x1) + dot4(e32, x2) + dot4(e33, x3);
#pragma unroll
                for (int off = 32; off > 0; off >>= 1) {  // 4-way interleaved butterflies
                    p0 += __shfl_xor(p0, off, 64);
                    p1 += __shfl_xor(p1, off, 64);
                    p2 += __shfl_xor(p2, off, 64);
                    p3 += __shfl_xor(p3, off, 64);
                }
                float v0 = (p0 == 0.0f) ? NEG_BIG : p0;  // torch quirk
                float v1 = (p1 == 0.0f) ? NEG_BIG : p1;
                float v2 = (p2 == 0.0f) ? NEG_BIG : p2;
                float v3 = (p3 == 0.0f) ? NEG_BIG : p3;
                if (lane == 0) {
                    scores[b * SS + srow + r + 0] = v0;
                    scores[b * SS + srow + r + 1] = v1;
                    scores[b * SS + srow + r + 2] = v2;
                    scores[b * SS + srow + r + 3] = v3;
                }
                float mm = fmaxf(m, fmaxf(fmaxf(v0, v1), fmaxf(v2, v3)));
                float sc = __expf(m - mm);  // == 1.0 when mm == m
                m = mm;
                l *= sc;
                a0.x *= sc; a0.y *= sc; a0.z *= sc; a0.w *= sc;
                a1.x *= sc; a1.y *= sc; a1.z *= sc; a1.w *= sc;
                a2.x *= sc; a2.y *= sc; a2.z *= sc; a2.w *= sc;
                a3.x *= sc; a3.y *= sc; a3.z *= sc; a3.w *= sc;
                float q0 = __expf(v0 - mm), q1 = __expf(v1 - mm);
                float q2 = __expf(v2 - mm), q3 = __expf(v3 - mm);
                l += q0 + q1 + q2 + q3;
                a0.x += q0 * e00.x + q1 * e10.x + q2 * e20.x + q3 * e30.x;
                a0.y += q0 * e00.y + q1 * e10.y + q2 * e20.y + q3 * e30.y;
                a0.z += q0 * e00.z + q1 * e10.z + q2 * e20.z + q3 * e30.z;
                a0.w += q0 * e00.w + q1 * e10.w + q2 * e20.w + q3 * e30.w;
                a1.x += q0 * e01.x + q1 * e11.x + q2 * e21.x + q3 * e31.x;
                a1.y += q0 * e01.y + q1 * e11.y + q2 * e21.y + q3 * e31.y;
                a1.z += q0 * e01.z + q1 * e11.z + q2 * e21.z + q3 * e31.z;
                a1.w += q0 * e01.w + q1 * e11.w + q2 * e21.w + q3 * e31.w;
                a2.x += q0 * e02.x + q1 * e12.x + q2 * e22.x + q3 * e32.x;
                a2.y += q0 * e02.y + q1 * e12.y + q2 * e22.y + q3 * e32.y;
                a2.z += q0 * e02.z + q1 * e12.z + q2 * e22.z + q3 * e32.z;
                a2.w += q0 * e02.w + q1 * e12.w + q2 * e22.w + q3 * e32.w;
                a3.x += q0 * e03.x + q1 * e13.x + q2 * e23.x + q3 * e33.x;
                a3.y += q0 * e03.y + q1 * e13.y + q2 * e23.y + q3 * e33.y;
                a3.z += q0 * e03.z + q1 * e13.z + q2 * e23.z + q3 * e33.z;
                a3.w += q0 * e03.w + q1 * e13.w + q2 * e23.w + q3 * e33.w;
            }
            for (; r < rend; ++r) {  // tail (0..3 rows)
                const float4* ep = (const float4*)(erow + (size_t)r * DD);
                float4 e0 = ep[lane], e1 = ep[lane + 64], e2 = ep[lane + 128], e3 = ep[lane + 192];
                float p0 = dot4(e0, x0) + dot4(e1, x1) + dot4(e2, x2) + dot4(e3, x3);
                p0 = wave_reduce_sum(p0);
                float v0 = (p0 == 0.0f) ? NEG_BIG : p0;
                if (lane == 0) scores[b * SS + srow + r] = v0;
                float mm = fmaxf(m, v0);
                float sc = __expf(m - mm);
                m = mm;
                l *= sc;
                a0.x *= sc; a0.y *= sc; a0.z *= sc; a0.w *= sc;
                a1.x *= sc; a1.y *= sc; a1.z *= sc; a1.w *= sc;
                a2.x *= sc; a2.y *= sc; a2.z *= sc; a2.w *= sc;
                a3.x *= sc; a3.y *= sc; a3.z *= sc; a3.w *= sc;
                float q0 = __expf(v0 - mm);
                l += q0;
                a0.x += q0 * e0.x; a0.y += q0 * e0.y; a0.z += q0 * e0.z; a0.w += q0 * e0.w;
                a1.x += q0 * e1.x; a1.y += q0 * e1.y; a1.z += q0 * e1.z; a1.w += q0 * e1.w;
                a2.x += q0 * e2.x; a2.y += q0 * e2.y; a2.z += q0 * e2.z; a2.w += q0 * e2.w;
                a3.x += q0 * e3.x; a3.y += q0 * e3.y; a3.z += q0 * e3.z; a3.w += q0 * e3.w;
            }
        }
        // rows >= len: untouched; attn.T emits 0 for them (exp(-1e10-M)==0).

        lctx[w][lane] = a0;
        lctx[w][lane + 64] = a1;
        lctx[w][lane + 128] = a2;
        lctx[w][lane + 192] = a3;
        if (lane == 0) { lm[w] = m; ll[w] = l; }
        __syncthreads();

        if (tid < 256) {
            float M = lm[0];
#pragma unroll
            for (int k = 1; k < 8; ++k) M = fmaxf(M, lm[k]);
            float L = 0.f;
            float4 sum = {0, 0, 0, 0};
#pragma unroll
            for (int k = 0; k < 8; ++k) {
                float sc = __expf(lm[k] - M);  // empty waves contribute 0
                L += sc * ll[k];
                float4 c = lctx[k][tid];
                sum.x += sc * c.x; sum.y += sc * c.y; sum.z += sc * c.z; sum.w += sc * c.w;
            }
            int cc = ((tid >> 6) << 8) | ((tid & 63) << 2);
            *(float4*)(ctxp + ((size_t)(b * NSPLIT + sp)) * DD + cc) = sum;
            if (tid == 0) {
                m_part[b * NSPLIT + sp] = M;
                l_part[b * NSPLIT + sp] = L;
            }
        }
        // ---- fan-in: last block for batch b combines its partials ----
        __threadfence();   // release this block's ctxp/m_part/l_part writes
        __syncthreads();
        if (tid == 0) {
            int old = atomicAdd(&cnt[b], 1);
            lastflag = (old == nb - 1);
        }
        __syncthreads();
        if (lastflag) {
            __threadfence();  // acquire: see all blocks' partials
            if (tid == 0) {
                float M = NEG_BIG;
                for (int k = 0; k < nb; ++k) M = fmaxf(M, m_part[b * NSPLIT + k]);
                float L = 0.f;
                for (int k = 0; k < nb; ++k) L += __expf(m_part[b * NSPLIT + k] - M) * l_part[b * NSPLIT + k];
                sM = M; sL = L;
                Mb[b] = M; Lb[b] = L;
            }
            __syncthreads();
            float M = sM, rL = 1.0f / sL;
            float2 sum = {0.f, 0.f};
            for (int k = 0; k < nb; ++k) {
                float sc = __expf(m_part[b * NSPLIT + k] - M);
                float2 c = *(const float2*)(ctxp + ((size_t)(b * NSPLIT + k)) * DD + tid * 2);
                sum.x += sc * c.x;
                sum.y += sc * c.y;
            }
            float2 o = {sum.x * rL, sum.y * rL};
            *(float2*)(ctx + (size_t)b * DD + tid * 2) = o;
            if (tid == 0) {
                __threadfence();
                atomicExch(&cnt[b], 0);  // reset for next replay
            }
        }
        __syncthreads();  // protect lctx/lastflag reuse on next chunk
    }
}

// ---------------- K4: out GEMM split-K with fan-in tanh + attn.T ----------------
// grid 768, block 256. Blocks 0..511: GEMM (dt,ks) + last-block tanh reduce.
// Blocks 512..767: attn.T from scores/Mb/Lb.
__global__ __launch_bounds__(256) void k4_out(const float* __restrict__ ctx,
                                              const float* __restrict__ hidden,
                                              const float* __restrict__ W2,
                                              const float* __restrict__ scores,
                                              const int* __restrict__ src_lens,
                                              const float* __restrict__ Mb,
                                              const float* __restrict__ Lb,
                                              float* __restrict__ outp,
                                              float* __restrict__ out,
                                              int* __restrict__ cnt_d) {
    int blk = blockIdx.x;
    int tid = threadIdx.x;
    if (blk < 512) {
        int dt = blk & 31;
        int ks = blk >> 5;
        __shared__ float cat_s[32 * 128];
        __shared__ float w2_s[32 * 128];
        __shared__ int lastf;
        int b0 = tid & 15, b1 = b0 + 16;
        int dl0 = (tid >> 4) * 2, dl1 = dl0 + 1;
        float acc00 = 0.f, acc01 = 0.f, acc10 = 0.f, acc11 = 0.f;

        int j0 = ks * 128;
#pragma unroll
        for (int pass = 0; pass < 4; ++pass) {
            int r = pass * 8 + (tid >> 5);
            int jj4 = tid & 31;
            int j = j0 + jj4 * 4;
            const float* src = (j < 1024) ? (ctx + (size_t)r * 1024 + j)
                                          : (hidden + (size_t)r * 1024 + (j - 1024));
            float4 v = *(const float4*)src;
            *(float4*)(cat_s + r * 128 + ((jj4 ^ (r & 7)) << 2)) = v;
            int dg = dt * 32 + r;
            float4 wv = *(const float4*)(W2 + (size_t)dg * HD + j);
            *(float4*)(w2_s + r * 128 + ((jj4 ^ (r & 7)) << 2)) = wv;
        }
        __syncthreads();
#pragma unroll 4
        for (int jj4 = 0; jj4 < 32; ++jj4) {
            float4 cA = *(const float4*)(cat_s + b0 * 128 + ((jj4 ^ (b0 & 7)) << 2));
            float4 cB = *(const float4*)(cat_s + b1 * 128 + ((jj4 ^ (b1 & 7)) << 2));
            float4 wA = *(const float4*)(w2_s + dl0 * 128 + ((jj4 ^ (dl0 & 7)) << 2));
            float4 wB = *(const float4*)(w2_s + dl1 * 128 + ((jj4 ^ (dl1 & 7)) << 2));
            acc00 += dot4(cA, wA);
            acc01 += dot4(cA, wB);
            acc10 += dot4(cB, wA);
            acc11 += dot4(cB, wB);
        }
        float* op = outp + (size_t)ks * (BB * DD);
        op[b0 * 1024 + dt * 32 + dl0] = acc00;
        op[b0 * 1024 + dt * 32 + dl1] = acc01;
        op[b1 * 1024 + dt * 32 + dl0] = acc10;
        op[b1 * 1024 + dt * 32 + dl1] = acc11;

        // fan-in: last ks-block for this dtile sums partials and applies tanh
        __threadfence();
        __syncthreads();
        if (tid == 0) {
            int old = atomicAdd(&cnt_d[dt], 1);
            lastf = (old == KSPLIT - 1);
        }
        __syncthreads();
        if (lastf) {
            __threadfence();
            for (int t = tid; t < 1024; t += 256) {
                int bb = t >> 5, c = t & 31;
                float s = 0.f;
#pragma unroll
                for (int k = 0; k < KSPLIT; ++k)
                    s += outp[(size_t)k * (BB * DD) + bb * 1024 + dt * 32 + c];
                out[bb * 1024 + dt * 32 + c] = tanhf(s);
            }
            if (tid == 0) atomicExch(&cnt_d[dt], 0);  // reset for next replay
        }
    } else {
        int j = (blk - 512) * 256 + tid;  // attn.T index: j = s*B + b, 0..65535
        int b = j & 31, sIdx = j >> 5;
        float v = 0.0f;                   // rows >= len: exp(-1e10 - M) == 0 exactly
        if (sIdx < src_lens[b]) v = __expf(scores[b * SS + sIdx] - Mb[b]) / Lb[b];
        out[BB * DD + j] = v;
    }
}

extern "C" void kernel_launch(void* const* d_in, const int* in_sizes, int n_in,
                              void* d_out, int out_size, void* d_ws, size_t ws_size,
                              hipStream_t stream) {
    const float* hidden = (const float*)d_in[0];
    const float* enc = (const float*)d_in[1];
    const int* src_lens = (const int*)d_in[2];
    const float* W1 = (const float*)d_in[3];
    const float* W2 = (const float*)d_in[4];
    float* out = (float*)d_out;
    float* ws = (float*)d_ws;

    // ws layout (floats)
    float* x = ws;                       // 32768
    float* scores = ws + 32768;          // 65536
    float* ctxp = ws + 98304;            // 32*32*1024 = 1048576
    float* m_part = ws + 1146880;        // 1024
    float* l_part = ws + 1147904;        // 1024
    float* Mb = ws + 1148928;            // 32
    float* Lb = ws + 1148960;            // 32
    float* ctx = ws + 1148992;           // 32768
    float* outp = ws + 1181760;          // 16*32768 = 524288
    int* cnt = (int*)(ws + 1706048);     // 64 ints: [0..31] batch, [32..63] dtile

    k1_gemv_x<<<256, 256, 0, stream>>>(hidden, W1, x, cnt);
    k2_fused<<<512, 512, 0, stream>>>(enc, x, src_lens, scores, ctxp, m_part, l_part,
                                      ctx, Mb, Lb, cnt);
    k4_out<<<768, 256, 0, stream>>>(ctx, hidden, W2, scores, src_lens, Mb, Lb,
                                    outp, out, cnt + 32);
}

// Round 12
// 118.285 us; speedup vs baseline: 2.2768x; 2.2768x over previous
//
#include <hip/hip_runtime.h>
#include <hip/hip_bf16.h>
#include <math.h>

// Problem constants
#define BB 32
#define SS 2048
#define HH 1024
#define DD 1024
#define HD 2048
#define NSPLIT 32   // 64-row chunks per batch (max)
#define KSPLIT 16   // K-splits for out GEMM
#define NEG_BIG -1e10f

__device__ __forceinline__ float wave_reduce_sum(float v) {
#pragma unroll
    for (int off = 32; off > 0; off >>= 1) v += __shfl_xor(v, off, 64);
    return v;
}

__device__ __forceinline__ float dot4(float4 a, float4 b) {
    return a.x * b.x + a.y * b.y + a.z * b.z + a.w * b.w;
}

// ---------------- K1: x = hidden @ W1^T; zero K4's fan-in counters ----------------
// grid 512, block 256. Waves 2w,2w+1 share W1 row d (L1 reuse); each wave
// handles 16 batches (halved serial chain vs R8), pair-unrolled.
__global__ __launch_bounds__(256) void k1_gemv_x(const float* __restrict__ hidden,
                                                 const float* __restrict__ W1,
                                                 float* __restrict__ x,
                                                 int* __restrict__ cnt) {
    if (blockIdx.x == 0 && threadIdx.x < 32) cnt[threadIdx.x] = 0;  // K4 fan-in counters
    int tid = threadIdx.x;
    int w = tid >> 6, lane = tid & 63;
    int d = blockIdx.x * 2 + (w >> 1);
    int bbase = (w & 1) * 16;
    const float4* wp = (const float4*)(W1 + (size_t)d * HH);
    float4 w0 = wp[lane], w1 = wp[lane + 64], w2 = wp[lane + 128], w3 = wp[lane + 192];
    const float4* hp = (const float4*)hidden;
#pragma unroll
    for (int i = 0; i < 16; i += 2) {
        const float4* h0 = hp + (bbase + i) * 256;
        const float4* h1 = hp + (bbase + i + 1) * 256;
        float s0 = dot4(h0[lane], w0) + dot4(h0[lane + 64], w1) +
                   dot4(h0[lane + 128], w2) + dot4(h0[lane + 192], w3);
        float s1 = dot4(h1[lane], w0) + dot4(h1[lane + 64], w1) +
                   dot4(h1[lane + 128], w2) + dot4(h1[lane + 192], w3);
#pragma unroll
        for (int off = 32; off > 0; off >>= 1) {
            s0 += __shfl_xor(s0, off, 64);
            s1 += __shfl_xor(s1, off, 64);
        }
        if (lane == 0) {
            x[(bbase + i) * DD + d] = s0;
            x[(bbase + i + 1) * DD + d] = s1;
        }
    }
}

// ---------------- K2: fused scores + online-softmax ctx partials (R8-exact) ----------------
// grid 512, block 512 (8 waves x 8 rows per 64-row chunk). NO fences here.
__global__ __launch_bounds__(512) void k2_fused(const float* __restrict__ enc,
                                                const float* __restrict__ x,
                                                const int* __restrict__ src_lens,
                                                float* __restrict__ scores,
                                                float* __restrict__ ctxp,
                                                float* __restrict__ m_part,
                                                float* __restrict__ l_part) {
    int tid = threadIdx.x;
    int w = tid >> 6, lane = tid & 63;

    __shared__ int pfx[BB + 1];
    if (tid == 0) {
        int a = 0;
        pfx[0] = 0;
#pragma unroll
        for (int b = 0; b < BB; ++b) {
            a += (src_lens[b] + 63) >> 6;
            pfx[b + 1] = a;
        }
    }
    __shared__ float4 lctx[8][256];  // 32 KB
    __shared__ float lm[8], ll[8];
    __syncthreads();
    int total = pfx[BB];

    for (int chunk = blockIdx.x; chunk < total; chunk += gridDim.x) {
        int b = 0;
        while (pfx[b + 1] <= chunk) ++b;  // uniform, <=32 iters
        int sp = chunk - pfx[b];
        int len = src_lens[b];
        int srow = sp * 64 + w * 8;

        float m = NEG_BIG, l = 0.f;
        float4 a0 = {0, 0, 0, 0}, a1 = {0, 0, 0, 0}, a2 = {0, 0, 0, 0}, a3 = {0, 0, 0, 0};

        if (srow < len) {
            const float4* xp = (const float4*)(x + (size_t)b * DD);
            float4 x0 = xp[lane], x1 = xp[lane + 64], x2 = xp[lane + 128], x3 = xp[lane + 192];
            int rend = min(8, len - srow);
            const float* erow = enc + ((size_t)b * SS + srow) * DD;
            int r = 0;
            for (; r + 4 <= rend; r += 4) {
                const float4* pr0 = (const float4*)(erow + (size_t)(r + 0) * DD);
                const float4* pr1 = (const float4*)(erow + (size_t)(r + 1) * DD);
                const float4* pr2 = (const float4*)(erow + (size_t)(r + 2) * DD);
                const float4* pr3 = (const float4*)(erow + (size_t)(r + 3) * DD);
                float4 e00 = pr0[lane], e01 = pr0[lane + 64], e02 = pr0[lane + 128], e03 = pr0[lane + 192];
                float4 e10 = pr1[lane], e11 = pr1[lane + 64], e12 = pr1[lane + 128], e13 = pr1[lane + 192];
                float4 e20 = pr2[lane], e21 = pr2[lane + 64], e22 = pr2[lane + 128], e23 = pr2[lane + 192];
                float4 e30 = pr3[lane], e31 = pr3[lane + 64], e32 = pr3[lane + 128], e33 = pr3[lane + 192];
                float p0 = dot4(e00, x0) + dot4(e01, x1) + dot4(e02, x2) + dot4(e03, x3);
                float p1 = dot4(e10, x0) + dot4(e11, x1) + dot4(e12, x2) + dot4(e13, x3);
                float p2 = dot4(e20, x0) + dot4(e21, x1) + dot4(e22, x2) + dot4(e23, x3);
                float p3 = dot4(e30, x0) + dot4(e31, x1) + dot4(e32, x2) + dot4(e33, x3);
#pragma unroll
                for (int off = 32; off > 0; off >>= 1) {  // 4-way interleaved butterflies
                    p0 += __shfl_xor(p0, off, 64);
                    p1 += __shfl_xor(p1, off, 64);
                    p2 += __shfl_xor(p2, off, 64);
                    p3 += __shfl_xor(p3, off, 64);
                }
                float v0 = (p0 == 0.0f) ? NEG_BIG : p0;  // torch quirk
                float v1 = (p1 == 0.0f) ? NEG_BIG : p1;
                float v2 = (p2 == 0.0f) ? NEG_BIG : p2;
                float v3 = (p3 == 0.0f) ? NEG_BIG : p3;
                if (lane == 0) {
                    scores[b * SS + srow + r + 0] = v0;
                    scores[b * SS + srow + r + 1] = v1;
                    scores[b * SS + srow + r + 2] = v2;
                    scores[b * SS + srow + r + 3] = v3;
                }
                float mm = fmaxf(m, fmaxf(fmaxf(v0, v1), fmaxf(v2, v3)));
                float sc = __expf(m - mm);  // == 1.0 when mm == m
                m = mm;
                l *= sc;
                a0.x *= sc; a0.y *= sc; a0.z *= sc; a0.w *= sc;
                a1.x *= sc; a1.y *= sc; a1.z *= sc; a1.w *= sc;
                a2.x *= sc; a2.y *= sc; a2.z *= sc; a2.w *= sc;
                a3.x *= sc; a3.y *= sc; a3.z *= sc; a3.w *= sc;
                float q0 = __expf(v0 - mm), q1 = __expf(v1 - mm);
                float q2 = __expf(v2 - mm), q3 = __expf(v3 - mm);
                l += q0 + q1 + q2 + q3;
                a0.x += q0 * e00.x + q1 * e10.x + q2 * e20.x + q3 * e30.x;
                a0.y += q0 * e00.y + q1 * e10.y + q2 * e20.y + q3 * e30.y;
                a0.z += q0 * e00.z + q1 * e10.z + q2 * e20.z + q3 * e30.z;
                a0.w += q0 * e00.w + q1 * e10.w + q2 * e20.w + q3 * e30.w;
                a1.x += q0 * e01.x + q1 * e11.x + q2 * e21.x + q3 * e31.x;
                a1.y += q0 * e01.y + q1 * e11.y + q2 * e21.y + q3 * e31.y;
                a1.z += q0 * e01.z + q1 * e11.z + q2 * e21.z + q3 * e31.z;
                a1.w += q0 * e01.w + q1 * e11.w + q2 * e21.w + q3 * e31.w;
                a2.x += q0 * e02.x + q1 * e12.x + q2 * e22.x + q3 * e32.x;
                a2.y += q0 * e02.y + q1 * e12.y + q2 * e22.y + q3 * e32.y;
                a2.z += q0 * e02.z + q1 * e12.z + q2 * e22.z + q3 * e32.z;
                a2.w += q0 * e02.w + q1 * e12.w + q2 * e22.w + q3 * e32.w;
                a3.x += q0 * e03.x + q1 * e13.x + q2 * e23.x + q3 * e33.x;
                a3.y += q0 * e03.y + q1 * e13.y + q2 * e23.y + q3 * e33.y;
                a3.z += q0 * e03.z + q1 * e13.z + q2 * e23.z + q3 * e33.z;
                a3.w += q0 * e03.w + q1 * e13.w + q2 * e23.w + q3 * e33.w;
            }
            for (; r < rend; ++r) {  // tail (0..3 rows)
                const float4* ep = (const float4*)(erow + (size_t)r * DD);
                float4 e0 = ep[lane], e1 = ep[lane + 64], e2 = ep[lane + 128], e3 = ep[lane + 192];
                float p0 = dot4(e0, x0) + dot4(e1, x1) + dot4(e2, x2) + dot4(e3, x3);
                p0 = wave_reduce_sum(p0);
                float v0 = (p0 == 0.0f) ? NEG_BIG : p0;
                if (lane == 0) scores[b * SS + srow + r] = v0;
                float mm = fmaxf(m, v0);
                float sc = __expf(m - mm);
                m = mm;
                l *= sc;
                a0.x *= sc; a0.y *= sc; a0.z *= sc; a0.w *= sc;
                a1.x *= sc; a1.y *= sc; a1.z *= sc; a1.w *= sc;
                a2.x *= sc; a2.y *= sc; a2.z *= sc; a2.w *= sc;
                a3.x *= sc; a3.y *= sc; a3.z *= sc; a3.w *= sc;
                float q0 = __expf(v0 - mm);
                l += q0;
                a0.x += q0 * e0.x; a0.y += q0 * e0.y; a0.z += q0 * e0.z; a0.w += q0 * e0.w;
                a1.x += q0 * e1.x; a1.y += q0 * e1.y; a1.z += q0 * e1.z; a1.w += q0 * e1.w;
                a2.x += q0 * e2.x; a2.y += q0 * e2.y; a2.z += q0 * e2.z; a2.w += q0 * e2.w;
                a3.x += q0 * e3.x; a3.y += q0 * e3.y; a3.z += q0 * e3.z; a3.w += q0 * e3.w;
            }
        }
        // rows >= len: untouched; attn.T emits 0 for them (exp(-1e10-M)==0).

        lctx[w][lane] = a0;
        lctx[w][lane + 64] = a1;
        lctx[w][lane + 128] = a2;
        lctx[w][lane + 192] = a3;
        if (lane == 0) { lm[w] = m; ll[w] = l; }
        __syncthreads();

        if (tid < 256) {
            float M = lm[0];
#pragma unroll
            for (int k = 1; k < 8; ++k) M = fmaxf(M, lm[k]);
            float L = 0.f;
            float4 sum = {0, 0, 0, 0};
#pragma unroll
            for (int k = 0; k < 8; ++k) {
                float sc = __expf(lm[k] - M);  // empty waves contribute 0
                L += sc * ll[k];
                float4 c = lctx[k][tid];
                sum.x += sc * c.x; sum.y += sc * c.y; sum.z += sc * c.z; sum.w += sc * c.w;
            }
            int cc = ((tid >> 6) << 8) | ((tid & 63) << 2);
            *(float4*)(ctxp + ((size_t)(b * NSPLIT + sp)) * DD + cc) = sum;
            if (tid == 0) {
                m_part[b * NSPLIT + sp] = M;
                l_part[b * NSPLIT + sp] = L;
            }
        }
        __syncthreads();  // protect lctx reuse on next chunk
    }
}

// ---------------- K3: combine busy partials -> ctx, Mb, Lb ----------------
__global__ __launch_bounds__(256) void k3_combine(const float* __restrict__ ctxp,
                                                  const float* __restrict__ m_part,
                                                  const float* __restrict__ l_part,
                                                  const int* __restrict__ src_lens,
                                                  float* __restrict__ ctx,
                                                  float* __restrict__ Mb,
                                                  float* __restrict__ Lb) {
    int b = blockIdx.x >> 2;
    int col = (blockIdx.x & 3) * 256 + threadIdx.x;
    int nb = (src_lens[b] + 63) >> 6;  // busy chunks for this batch
    float M = NEG_BIG;
    for (int k = 0; k < nb; ++k) M = fmaxf(M, m_part[b * NSPLIT + k]);
    float L = 0.f;
    float sum = 0.f;
    for (int k = 0; k < nb; ++k) {
        float sc = __expf(m_part[b * NSPLIT + k] - M);
        L += sc * l_part[b * NSPLIT + k];
        sum += sc * ctxp[((size_t)(b * NSPLIT + k)) * DD + col];
    }
    ctx[(size_t)b * DD + col] = sum / L;
    if (threadIdx.x == 0 && (blockIdx.x & 3) == 0) { Mb[b] = M; Lb[b] = L; }
}

// ---------------- K4: out GEMM split-K w/ once-per-block fan-in tanh; attn.T ----------------
// grid 768, block 256. Blocks 0..511: GEMM (dt,ks); LAST ks-block of each dtile
// sums partials + tanh -> out. Blocks 512..767: attn.T. Fence ONCE per block.
__global__ __launch_bounds__(256) void k4_out(const float* __restrict__ ctx,
                                              const float* __restrict__ hidden,
                                              const float* __restrict__ W2,
                                              const float* __restrict__ scores,
                                              const int* __restrict__ src_lens,
                                              const float* __restrict__ Mb,
                                              const float* __restrict__ Lb,
                                              float* __restrict__ outp,
                                              float* __restrict__ out,
                                              int* __restrict__ cnt_d) {
    int blk = blockIdx.x;
    int tid = threadIdx.x;
    if (blk < 512) {
        int dt = blk & 31;
        int ks = blk >> 5;
        __shared__ float cat_s[32 * 128];
        __shared__ float w2_s[32 * 128];
        __shared__ int lastf;
        int b0 = tid & 15, b1 = b0 + 16;
        int dl0 = (tid >> 4) * 2, dl1 = dl0 + 1;
        float acc00 = 0.f, acc01 = 0.f, acc10 = 0.f, acc11 = 0.f;

        int j0 = ks * 128;
#pragma unroll
        for (int pass = 0; pass < 4; ++pass) {
            int r = pass * 8 + (tid >> 5);
            int jj4 = tid & 31;
            int j = j0 + jj4 * 4;
            const float* src = (j < 1024) ? (ctx + (size_t)r * 1024 + j)
                                          : (hidden + (size_t)r * 1024 + (j - 1024));
            float4 v = *(const float4*)src;
            *(float4*)(cat_s + r * 128 + ((jj4 ^ (r & 7)) << 2)) = v;
            int dg = dt * 32 + r;
            float4 wv = *(const float4*)(W2 + (size_t)dg * HD + j);
            *(float4*)(w2_s + r * 128 + ((jj4 ^ (r & 7)) << 2)) = wv;
        }
        __syncthreads();
#pragma unroll 4
        for (int jj4 = 0; jj4 < 32; ++jj4) {
            float4 cA = *(const float4*)(cat_s + b0 * 128 + ((jj4 ^ (b0 & 7)) << 2));
            float4 cB = *(const float4*)(cat_s + b1 * 128 + ((jj4 ^ (b1 & 7)) << 2));
            float4 wA = *(const float4*)(w2_s + dl0 * 128 + ((jj4 ^ (dl0 & 7)) << 2));
            float4 wB = *(const float4*)(w2_s + dl1 * 128 + ((jj4 ^ (dl1 & 7)) << 2));
            acc00 += dot4(cA, wA);
            acc01 += dot4(cA, wB);
            acc10 += dot4(cB, wA);
            acc11 += dot4(cB, wB);
        }
        float* op = outp + (size_t)ks * (BB * DD);
        op[b0 * 1024 + dt * 32 + dl0] = acc00;
        op[b0 * 1024 + dt * 32 + dl1] = acc01;
        op[b1 * 1024 + dt * 32 + dl0] = acc10;
        op[b1 * 1024 + dt * 32 + dl1] = acc11;

        // fan-in (ONCE per block): last ks-block of this dtile reduces + tanh
        __threadfence();
        __syncthreads();
        if (tid == 0) {
            int old = atomicAdd(&cnt_d[dt], 1);
            lastf = (old == KSPLIT - 1);
        }
        __syncthreads();
        if (lastf) {
            __threadfence();
            for (int t = tid; t < 1024; t += 256) {
                int bb = t >> 5, c = t & 31;
                float s = 0.f;
#pragma unroll
                for (int k = 0; k < KSPLIT; ++k)
                    s += outp[(size_t)k * (BB * DD) + bb * 1024 + dt * 32 + c];
                out[bb * 1024 + dt * 32 + c] = tanhf(s);
            }
            if (tid == 0) atomicExch(&cnt_d[dt], 0);  // reset for next replay
        }
    } else {
        int j = (blk - 512) * 256 + tid;  // attn.T index: j = s*B + b, 0..65535
        int b = j & 31, sIdx = j >> 5;
        float v = 0.0f;                   // rows >= len: exp(-1e10 - M) == 0 exactly
        if (sIdx < src_lens[b]) v = __expf(scores[b * SS + sIdx] - Mb[b]) / Lb[b];
        out[BB * DD + j] = v;
    }
}

extern "C" void kernel_launch(void* const* d_in, const int* in_sizes, int n_in,
                              void* d_out, int out_size, void* d_ws, size_t ws_size,
                              hipStream_t stream) {
    const float* hidden = (const float*)d_in[0];
    const float* enc = (const float*)d_in[1];
    const int* src_lens = (const int*)d_in[2];
    const float* W1 = (const float*)d_in[3];
    const float* W2 = (const float*)d_in[4];
    float* out = (float*)d_out;
    float* ws = (float*)d_ws;

    // ws layout (floats)
    float* x = ws;                       // 32768
    float* scores = ws + 32768;          // 65536
    float* ctxp = ws + 98304;            // 32*32*1024 = 1048576
    float* m_part = ws + 1146880;        // 1024
    float* l_part = ws + 1147904;        // 1024
    float* Mb = ws + 1148928;            // 32
    float* Lb = ws + 1148960;            // 32
    float* ctx = ws + 1148992;           // 32768
    float* outp = ws + 1181760;          // 16*32768 = 524288
    int* cnt = (int*)(ws + 1706048);     // 32 ints: dtile fan-in counters

    k1_gemv_x<<<512, 256, 0, stream>>>(hidden, W1, x, cnt);
    k2_fused<<<512, 512, 0, stream>>>(enc, x, src_lens, scores, ctxp, m_part, l_part);
    k3_combine<<<128, 256, 0, stream>>>(ctxp, m_part, l_part, src_lens, ctx, Mb, Lb);
    k4_out<<<768, 256, 0, stream>>>(ctx, hidden, W2, scores, src_lens, Mb, Lb,
                                    outp, out, cnt);
}

// Round 13
// 94.066 us; speedup vs baseline: 2.8630x; 1.2575x over previous
//
#include <hip/hip_runtime.h>
#include <hip/hip_bf16.h>
#include <math.h>

// Problem constants
#define BB 32
#define SS 2048
#define HH 1024
#define DD 1024
#define HD 2048
#define NSPLIT 32   // 64-row chunks per batch (max)
#define NEG_BIG -1e10f

__device__ __forceinline__ float wave_reduce_sum(float v) {
#pragma unroll
    for (int off = 32; off > 0; off >>= 1) v += __shfl_xor(v, off, 64);
    return v;
}

__device__ __forceinline__ float dot4(float4 a, float4 b) {
    return a.x * b.x + a.y * b.y + a.z * b.z + a.w * b.w;
}

// ---------------- K1: x = hidden @ W1^T  (B x D) ---- R8-exact ----------------
__global__ __launch_bounds__(256) void k1_gemv_x(const float* __restrict__ hidden,
                                                 const float* __restrict__ W1,
                                                 float* __restrict__ x) {
    __shared__ float4 hs[16 * 256];  // 64 KB: 16 batches of hidden
    int tid = threadIdx.x;
    int w = tid >> 6, lane = tid & 63;
    int d = blockIdx.x * 4 + w;
    const float4* wp = (const float4*)(W1 + (size_t)d * HH);
    float4 w0 = wp[lane], w1 = wp[lane + 64], w2 = wp[lane + 128], w3 = wp[lane + 192];
    const float4* hp = (const float4*)hidden;

    for (int half = 0; half < 2; ++half) {
        __syncthreads();
#pragma unroll
        for (int i = 0; i < 16; ++i) hs[i * 256 + tid] = hp[half * 4096 + i * 256 + tid];
        __syncthreads();
#pragma unroll
        for (int bl = 0; bl < 16; bl += 2) {
            const float4* hb0 = hs + bl * 256;
            const float4* hb1 = hs + (bl + 1) * 256;
            float s0 = dot4(hb0[lane], w0) + dot4(hb0[lane + 64], w1) +
                       dot4(hb0[lane + 128], w2) + dot4(hb0[lane + 192], w3);
            float s1 = dot4(hb1[lane], w0) + dot4(hb1[lane + 64], w1) +
                       dot4(hb1[lane + 128], w2) + dot4(hb1[lane + 192], w3);
#pragma unroll
            for (int off = 32; off > 0; off >>= 1) {
                s0 += __shfl_xor(s0, off, 64);
                s1 += __shfl_xor(s1, off, 64);
            }
            if (lane == 0) {
                x[(half * 16 + bl) * DD + d] = s0;
                x[(half * 16 + bl + 1) * DD + d] = s1;
            }
        }
    }
}

// ---------------- K2: fused scores + online-softmax ctx partials ---- R8-exact ----------------
__global__ __launch_bounds__(512) void k2_fused(const float* __restrict__ enc,
                                                const float* __restrict__ x,
                                                const int* __restrict__ src_lens,
                                                float* __restrict__ scores,
                                                float* __restrict__ ctxp,
                                                float* __restrict__ m_part,
                                                float* __restrict__ l_part) {
    int tid = threadIdx.x;
    int w = tid >> 6, lane = tid & 63;

    __shared__ int pfx[BB + 1];
    if (tid == 0) {
        int a = 0;
        pfx[0] = 0;
#pragma unroll
        for (int b = 0; b < BB; ++b) {
            a += (src_lens[b] + 63) >> 6;
            pfx[b + 1] = a;
        }
    }
    __shared__ float4 lctx[8][256];  // 32 KB
    __shared__ float lm[8], ll[8];
    __syncthreads();
    int total = pfx[BB];

    for (int chunk = blockIdx.x; chunk < total; chunk += gridDim.x) {
        int b = 0;
        while (pfx[b + 1] <= chunk) ++b;  // uniform, <=32 iters
        int sp = chunk - pfx[b];
        int len = src_lens[b];
        int srow = sp * 64 + w * 8;

        float m = NEG_BIG, l = 0.f;
        float4 a0 = {0, 0, 0, 0}, a1 = {0, 0, 0, 0}, a2 = {0, 0, 0, 0}, a3 = {0, 0, 0, 0};

        if (srow < len) {
            const float4* xp = (const float4*)(x + (size_t)b * DD);
            float4 x0 = xp[lane], x1 = xp[lane + 64], x2 = xp[lane + 128], x3 = xp[lane + 192];
            int rend = min(8, len - srow);
            const float* erow = enc + ((size_t)b * SS + srow) * DD;
            int r = 0;
            for (; r + 4 <= rend; r += 4) {
                const float4* pr0 = (const float4*)(erow + (size_t)(r + 0) * DD);
                const float4* pr1 = (const float4*)(erow + (size_t)(r + 1) * DD);
                const float4* pr2 = (const float4*)(erow + (size_t)(r + 2) * DD);
                const float4* pr3 = (const float4*)(erow + (size_t)(r + 3) * DD);
                float4 e00 = pr0[lane], e01 = pr0[lane + 64], e02 = pr0[lane + 128], e03 = pr0[lane + 192];
                float4 e10 = pr1[lane], e11 = pr1[lane + 64], e12 = pr1[lane + 128], e13 = pr1[lane + 192];
                float4 e20 = pr2[lane], e21 = pr2[lane + 64], e22 = pr2[lane + 128], e23 = pr2[lane + 192];
                float4 e30 = pr3[lane], e31 = pr3[lane + 64], e32 = pr3[lane + 128], e33 = pr3[lane + 192];
                float p0 = dot4(e00, x0) + dot4(e01, x1) + dot4(e02, x2) + dot4(e03, x3);
                float p1 = dot4(e10, x0) + dot4(e11, x1) + dot4(e12, x2) + dot4(e13, x3);
                float p2 = dot4(e20, x0) + dot4(e21, x1) + dot4(e22, x2) + dot4(e23, x3);
                float p3 = dot4(e30, x0) + dot4(e31, x1) + dot4(e32, x2) + dot4(e33, x3);
#pragma unroll
                for (int off = 32; off > 0; off >>= 1) {  // 4-way interleaved butterflies
                    p0 += __shfl_xor(p0, off, 64);
                    p1 += __shfl_xor(p1, off, 64);
                    p2 += __shfl_xor(p2, off, 64);
                    p3 += __shfl_xor(p3, off, 64);
                }
                float v0 = (p0 == 0.0f) ? NEG_BIG : p0;  // torch quirk
                float v1 = (p1 == 0.0f) ? NEG_BIG : p1;
                float v2 = (p2 == 0.0f) ? NEG_BIG : p2;
                float v3 = (p3 == 0.0f) ? NEG_BIG : p3;
                if (lane == 0) {
                    scores[b * SS + srow + r + 0] = v0;
                    scores[b * SS + srow + r + 1] = v1;
                    scores[b * SS + srow + r + 2] = v2;
                    scores[b * SS + srow + r + 3] = v3;
                }
                float mm = fmaxf(m, fmaxf(fmaxf(v0, v1), fmaxf(v2, v3)));
                float sc = __expf(m - mm);  // == 1.0 when mm == m
                m = mm;
                l *= sc;
                a0.x *= sc; a0.y *= sc; a0.z *= sc; a0.w *= sc;
                a1.x *= sc; a1.y *= sc; a1.z *= sc; a1.w *= sc;
                a2.x *= sc; a2.y *= sc; a2.z *= sc; a2.w *= sc;
                a3.x *= sc; a3.y *= sc; a3.z *= sc; a3.w *= sc;
                float q0 = __expf(v0 - mm), q1 = __expf(v1 - mm);
                float q2 = __expf(v2 - mm), q3 = __expf(v3 - mm);
                l += q0 + q1 + q2 + q3;
                a0.x += q0 * e00.x + q1 * e10.x + q2 * e20.x + q3 * e30.x;
                a0.y += q0 * e00.y + q1 * e10.y + q2 * e20.y + q3 * e30.y;
                a0.z += q0 * e00.z + q1 * e10.z + q2 * e20.z + q3 * e30.z;
                a0.w += q0 * e00.w + q1 * e10.w + q2 * e20.w + q3 * e30.w;
                a1.x += q0 * e01.x + q1 * e11.x + q2 * e21.x + q3 * e31.x;
                a1.y += q0 * e01.y + q1 * e11.y + q2 * e21.y + q3 * e31.y;
                a1.z += q0 * e01.z + q1 * e11.z + q2 * e21.z + q3 * e31.z;
                a1.w += q0 * e01.w + q1 * e11.w + q2 * e21.w + q3 * e31.w;
                a2.x += q0 * e02.x + q1 * e12.x + q2 * e22.x + q3 * e32.x;
                a2.y += q0 * e02.y + q1 * e12.y + q2 * e22.y + q3 * e32.y;
                a2.z += q0 * e02.z + q1 * e12.z + q2 * e22.z + q3 * e32.z;
                a2.w += q0 * e02.w + q1 * e12.w + q2 * e22.w + q3 * e32.w;
                a3.x += q0 * e03.x + q1 * e13.x + q2 * e23.x + q3 * e33.x;
                a3.y += q0 * e03.y + q1 * e13.y + q2 * e23.y + q3 * e33.y;
                a3.z += q0 * e03.z + q1 * e13.z + q2 * e23.z + q3 * e33.z;
                a3.w += q0 * e03.w + q1 * e13.w + q2 * e23.w + q3 * e33.w;
            }
            for (; r < rend; ++r) {  // tail (0..3 rows)
                const float4* ep = (const float4*)(erow + (size_t)r * DD);
                float4 e0 = ep[lane], e1 = ep[lane + 64], e2 = ep[lane + 128], e3 = ep[lane + 192];
                float p0 = dot4(e0, x0) + dot4(e1, x1) + dot4(e2, x2) + dot4(e3, x3);
                p0 = wave_reduce_sum(p0);
                float v0 = (p0 == 0.0f) ? NEG_BIG : p0;
                if (lane == 0) scores[b * SS + srow + r] = v0;
                float mm = fmaxf(m, v0);
                float sc = __expf(m - mm);
                m = mm;
                l *= sc;
                a0.x *= sc; a0.y *= sc; a0.z *= sc; a0.w *= sc;
                a1.x *= sc; a1.y *= sc; a1.z *= sc; a1.w *= sc;
                a2.x *= sc; a2.y *= sc; a2.z *= sc; a2.w *= sc;
                a3.x *= sc; a3.y *= sc; a3.z *= sc; a3.w *= sc;
                float q0 = __expf(v0 - mm);
                l += q0;
                a0.x += q0 * e0.x; a0.y += q0 * e0.y; a0.z += q0 * e0.z; a0.w += q0 * e0.w;
                a1.x += q0 * e1.x; a1.y += q0 * e1.y; a1.z += q0 * e1.z; a1.w += q0 * e1.w;
                a2.x += q0 * e2.x; a2.y += q0 * e2.y; a2.z += q0 * e2.z; a2.w += q0 * e2.w;
                a3.x += q0 * e3.x; a3.y += q0 * e3.y; a3.z += q0 * e3.z; a3.w += q0 * e3.w;
            }
        }
        // rows >= len: untouched; attn.T emits 0 for them (exp(-1e10-M)==0).

        lctx[w][lane] = a0;
        lctx[w][lane + 64] = a1;
        lctx[w][lane + 128] = a2;
        lctx[w][lane + 192] = a3;
        if (lane == 0) { lm[w] = m; ll[w] = l; }
        __syncthreads();

        if (tid < 256) {
            float M = lm[0];
#pragma unroll
            for (int k = 1; k < 8; ++k) M = fmaxf(M, lm[k]);
            float L = 0.f;
            float4 sum = {0, 0, 0, 0};
#pragma unroll
            for (int k = 0; k < 8; ++k) {
                float sc = __expf(lm[k] - M);  // empty waves contribute 0
                L += sc * ll[k];
                float4 c = lctx[k][tid];
                sum.x += sc * c.x; sum.y += sc * c.y; sum.z += sc * c.z; sum.w += sc * c.w;
            }
            int cc = ((tid >> 6) << 8) | ((tid & 63) << 2);
            *(float4*)(ctxp + ((size_t)(b * NSPLIT + sp)) * DD + cc) = sum;
            if (tid == 0) {
                m_part[b * NSPLIT + sp] = M;
                l_part[b * NSPLIT + sp] = L;
            }
        }
        __syncthreads();  // protect lctx reuse on next chunk
    }
}

// ---------------- K3: combine busy partials -> ctx, Mb, Lb ---- R8-exact ----------------
__global__ __launch_bounds__(256) void k3_combine(const float* __restrict__ ctxp,
                                                  const float* __restrict__ m_part,
                                                  const float* __restrict__ l_part,
                                                  const int* __restrict__ src_lens,
                                                  float* __restrict__ ctx,
                                                  float* __restrict__ Mb,
                                                  float* __restrict__ Lb) {
    int b = blockIdx.x >> 2;
    int col = (blockIdx.x & 3) * 256 + threadIdx.x;
    int nb = (src_lens[b] + 63) >> 6;  // busy chunks for this batch
    float M = NEG_BIG;
    for (int k = 0; k < nb; ++k) M = fmaxf(M, m_part[b * NSPLIT + k]);
    float L = 0.f;
    float sum = 0.f;
    for (int k = 0; k < nb; ++k) {
        float sc = __expf(m_part[b * NSPLIT + k] - M);
        L += sc * l_part[b * NSPLIT + k];
        sum += sc * ctxp[((size_t)(b * NSPLIT + k)) * DD + col];
    }
    ctx[(size_t)b * DD + col] = sum / L;
    if (threadIdx.x == 0 && (blockIdx.x & 3) == 0) { Mb[b] = M; Lb[b] = L; }
}

// ---------------- K45: full-K out GEMM + fused tanh; attn.T ----------------
// grid 320, block 256. Blocks 0..63: 16-dcol tile x 32 batches, ALL 16 k-chunks
// accumulated in registers (same chunk order as old K5+K6 sum), tanh in-block.
// Blocks 64..319: attn.T from scores/Mb/Lb (K3 outputs). No fences, no atomics.
__global__ __launch_bounds__(256) void k45_out(const float* __restrict__ ctx,
                                               const float* __restrict__ hidden,
                                               const float* __restrict__ W2,
                                               const float* __restrict__ scores,
                                               const int* __restrict__ src_lens,
                                               const float* __restrict__ Mb,
                                               const float* __restrict__ Lb,
                                               float* __restrict__ out) {
    int blk = blockIdx.x;
    int tid = threadIdx.x;
    if (blk < 64) {
        int dt = blk;  // dcols dt*16 .. dt*16+15
        __shared__ float cat_s[32 * 128];  // 16 KB
        __shared__ float w2_s[16 * 128];   // 8 KB
        int b0 = tid & 15, b1 = b0 + 16;
        int dl = tid >> 4;  // 0..15
        float acc0 = 0.f, acc1 = 0.f;

        for (int ks = 0; ks < 16; ++ks) {
            int j0 = ks * 128;
            __syncthreads();  // protect prev-iter LDS reads
#pragma unroll
            for (int pass = 0; pass < 4; ++pass) {  // stage cat rows 0..31
                int r = pass * 8 + (tid >> 5);
                int jj4 = tid & 31;
                int j = j0 + jj4 * 4;
                const float* src = (j < 1024) ? (ctx + (size_t)r * 1024 + j)
                                              : (hidden + (size_t)r * 1024 + (j - 1024));
                float4 v = *(const float4*)src;
                *(float4*)(cat_s + r * 128 + ((jj4 ^ (r & 7)) << 2)) = v;
            }
#pragma unroll
            for (int pass = 0; pass < 2; ++pass) {  // stage W2 rows 0..15
                int r = pass * 8 + (tid >> 5);
                int jj4 = tid & 31;
                int j = j0 + jj4 * 4;
                float4 wv = *(const float4*)(W2 + (size_t)(dt * 16 + r) * HD + j);
                *(float4*)(w2_s + r * 128 + ((jj4 ^ (r & 7)) << 2)) = wv;
            }
            __syncthreads();
#pragma unroll 4
            for (int jj4 = 0; jj4 < 32; ++jj4) {
                float4 cA = *(const float4*)(cat_s + b0 * 128 + ((jj4 ^ (b0 & 7)) << 2));
                float4 cB = *(const float4*)(cat_s + b1 * 128 + ((jj4 ^ (b1 & 7)) << 2));
                float4 wA = *(const float4*)(w2_s + dl * 128 + ((jj4 ^ (dl & 7)) << 2));
                acc0 += dot4(cA, wA);
                acc1 += dot4(cB, wA);
            }
        }
        out[b0 * 1024 + dt * 16 + dl] = tanhf(acc0);
        out[b1 * 1024 + dt * 16 + dl] = tanhf(acc1);
    } else {
        int j = (blk - 64) * 256 + tid;  // attn.T index: j = s*B + b, 0..65535
        int b = j & 31, sIdx = j >> 5;
        float v = 0.0f;                  // rows >= len: exp(-1e10 - M) == 0 exactly
        if (sIdx < src_lens[b]) v = __expf(scores[b * SS + sIdx] - Mb[b]) / Lb[b];
        out[BB * DD + j] = v;
    }
}

extern "C" void kernel_launch(void* const* d_in, const int* in_sizes, int n_in,
                              void* d_out, int out_size, void* d_ws, size_t ws_size,
                              hipStream_t stream) {
    const float* hidden = (const float*)d_in[0];
    const float* enc = (const float*)d_in[1];
    const int* src_lens = (const int*)d_in[2];
    const float* W1 = (const float*)d_in[3];
    const float* W2 = (const float*)d_in[4];
    float* out = (float*)d_out;
    float* ws = (float*)d_ws;

    // ws layout (floats)
    float* x = ws;                       // 32768
    float* scores = ws + 32768;          // 65536
    float* ctxp = ws + 98304;            // 32*32*1024 = 1048576
    float* m_part = ws + 1146880;        // 1024
    float* l_part = ws + 1147904;        // 1024
    float* Mb = ws + 1148928;            // 32
    float* Lb = ws + 1148960;            // 32
    float* ctx = ws + 1148992;           // 32768  (total ~4.7 MB)

    k1_gemv_x<<<256, 256, 0, stream>>>(hidden, W1, x);
    k2_fused<<<512, 512, 0, stream>>>(enc, x, src_lens, scores, ctxp, m_part, l_part);
    k3_combine<<<128, 256, 0, stream>>>(ctxp, m_part, l_part, src_lens, ctx, Mb, Lb);
    k45_out<<<320, 256, 0, stream>>>(ctx, hidden, W2, scores, src_lens, Mb, Lb, out);
}

// Round 14
// 80.556 us; speedup vs baseline: 3.3432x; 1.1677x over previous
//
#include <hip/hip_runtime.h>
#include <hip/hip_bf16.h>
#include <math.h>

// Problem constants
#define BB 32
#define SS 2048
#define HH 1024
#define DD 1024
#define HD 2048
#define NSPLIT 32   // 64-row chunks per batch (max)
#define KSPLIT 16   // K-splits for out GEMM
#define NEG_BIG -1e10f

__device__ __forceinline__ float wave_reduce_sum(float v) {
#pragma unroll
    for (int off = 32; off > 0; off >>= 1) v += __shfl_xor(v, off, 64);
    return v;
}

__device__ __forceinline__ float dot4(float4 a, float4 b) {
    return a.x * b.x + a.y * b.y + a.z * b.z + a.w * b.w;
}

// ---------------- K1: x = hidden @ W1^T  (B x D) ---- R8-exact ----------------
__global__ __launch_bounds__(256) void k1_gemv_x(const float* __restrict__ hidden,
                                                 const float* __restrict__ W1,
                                                 float* __restrict__ x) {
    __shared__ float4 hs[16 * 256];  // 64 KB: 16 batches of hidden
    int tid = threadIdx.x;
    int w = tid >> 6, lane = tid & 63;
    int d = blockIdx.x * 4 + w;
    const float4* wp = (const float4*)(W1 + (size_t)d * HH);
    float4 w0 = wp[lane], w1 = wp[lane + 64], w2 = wp[lane + 128], w3 = wp[lane + 192];
    const float4* hp = (const float4*)hidden;

    for (int half = 0; half < 2; ++half) {
        __syncthreads();
#pragma unroll
        for (int i = 0; i < 16; ++i) hs[i * 256 + tid] = hp[half * 4096 + i * 256 + tid];
        __syncthreads();
#pragma unroll
        for (int bl = 0; bl < 16; bl += 2) {
            const float4* hb0 = hs + bl * 256;
            const float4* hb1 = hs + (bl + 1) * 256;
            float s0 = dot4(hb0[lane], w0) + dot4(hb0[lane + 64], w1) +
                       dot4(hb0[lane + 128], w2) + dot4(hb0[lane + 192], w3);
            float s1 = dot4(hb1[lane], w0) + dot4(hb1[lane + 64], w1) +
                       dot4(hb1[lane + 128], w2) + dot4(hb1[lane + 192], w3);
#pragma unroll
            for (int off = 32; off > 0; off >>= 1) {
                s0 += __shfl_xor(s0, off, 64);
                s1 += __shfl_xor(s1, off, 64);
            }
            if (lane == 0) {
                x[(half * 16 + bl) * DD + d] = s0;
                x[(half * 16 + bl + 1) * DD + d] = s1;
            }
        }
    }
}

// ---------------- K2: fused scores + online-softmax ctx partials ---- R8-exact ----------------
__global__ __launch_bounds__(512) void k2_fused(const float* __restrict__ enc,
                                                const float* __restrict__ x,
                                                const int* __restrict__ src_lens,
                                                float* __restrict__ scores,
                                                float* __restrict__ ctxp,
                                                float* __restrict__ m_part,
                                                float* __restrict__ l_part) {
    int tid = threadIdx.x;
    int w = tid >> 6, lane = tid & 63;

    __shared__ int pfx[BB + 1];
    if (tid == 0) {
        int a = 0;
        pfx[0] = 0;
#pragma unroll
        for (int b = 0; b < BB; ++b) {
            a += (src_lens[b] + 63) >> 6;
            pfx[b + 1] = a;
        }
    }
    __shared__ float4 lctx[8][256];  // 32 KB
    __shared__ float lm[8], ll[8];
    __syncthreads();
    int total = pfx[BB];

    for (int chunk = blockIdx.x; chunk < total; chunk += gridDim.x) {
        int b = 0;
        while (pfx[b + 1] <= chunk) ++b;  // uniform, <=32 iters
        int sp = chunk - pfx[b];
        int len = src_lens[b];
        int srow = sp * 64 + w * 8;

        float m = NEG_BIG, l = 0.f;
        float4 a0 = {0, 0, 0, 0}, a1 = {0, 0, 0, 0}, a2 = {0, 0, 0, 0}, a3 = {0, 0, 0, 0};

        if (srow < len) {
            const float4* xp = (const float4*)(x + (size_t)b * DD);
            float4 x0 = xp[lane], x1 = xp[lane + 64], x2 = xp[lane + 128], x3 = xp[lane + 192];
            int rend = min(8, len - srow);
            const float* erow = enc + ((size_t)b * SS + srow) * DD;
            int r = 0;
            for (; r + 4 <= rend; r += 4) {
                const float4* pr0 = (const float4*)(erow + (size_t)(r + 0) * DD);
                const float4* pr1 = (const float4*)(erow + (size_t)(r + 1) * DD);
                const float4* pr2 = (const float4*)(erow + (size_t)(r + 2) * DD);
                const float4* pr3 = (const float4*)(erow + (size_t)(r + 3) * DD);
                float4 e00 = pr0[lane], e01 = pr0[lane + 64], e02 = pr0[lane + 128], e03 = pr0[lane + 192];
                float4 e10 = pr1[lane], e11 = pr1[lane + 64], e12 = pr1[lane + 128], e13 = pr1[lane + 192];
                float4 e20 = pr2[lane], e21 = pr2[lane + 64], e22 = pr2[lane + 128], e23 = pr2[lane + 192];
                float4 e30 = pr3[lane], e31 = pr3[lane + 64], e32 = pr3[lane + 128], e33 = pr3[lane + 192];
                float p0 = dot4(e00, x0) + dot4(e01, x1) + dot4(e02, x2) + dot4(e03, x3);
                float p1 = dot4(e10, x0) + dot4(e11, x1) + dot4(e12, x2) + dot4(e13, x3);
                float p2 = dot4(e20, x0) + dot4(e21, x1) + dot4(e22, x2) + dot4(e23, x3);
                float p3 = dot4(e30, x0) + dot4(e31, x1) + dot4(e32, x2) + dot4(e33, x3);
#pragma unroll
                for (int off = 32; off > 0; off >>= 1) {  // 4-way interleaved butterflies
                    p0 += __shfl_xor(p0, off, 64);
                    p1 += __shfl_xor(p1, off, 64);
                    p2 += __shfl_xor(p2, off, 64);
                    p3 += __shfl_xor(p3, off, 64);
                }
                float v0 = (p0 == 0.0f) ? NEG_BIG : p0;  // torch quirk
                float v1 = (p1 == 0.0f) ? NEG_BIG : p1;
                float v2 = (p2 == 0.0f) ? NEG_BIG : p2;
                float v3 = (p3 == 0.0f) ? NEG_BIG : p3;
                if (lane == 0) {
                    scores[b * SS + srow + r + 0] = v0;
                    scores[b * SS + srow + r + 1] = v1;
                    scores[b * SS + srow + r + 2] = v2;
                    scores[b * SS + srow + r + 3] = v3;
                }
                float mm = fmaxf(m, fmaxf(fmaxf(v0, v1), fmaxf(v2, v3)));
                float sc = __expf(m - mm);  // == 1.0 when mm == m
                m = mm;
                l *= sc;
                a0.x *= sc; a0.y *= sc; a0.z *= sc; a0.w *= sc;
                a1.x *= sc; a1.y *= sc; a1.z *= sc; a1.w *= sc;
                a2.x *= sc; a2.y *= sc; a2.z *= sc; a2.w *= sc;
                a3.x *= sc; a3.y *= sc; a3.z *= sc; a3.w *= sc;
                float q0 = __expf(v0 - mm), q1 = __expf(v1 - mm);
                float q2 = __expf(v2 - mm), q3 = __expf(v3 - mm);
                l += q0 + q1 + q2 + q3;
                a0.x += q0 * e00.x + q1 * e10.x + q2 * e20.x + q3 * e30.x;
                a0.y += q0 * e00.y + q1 * e10.y + q2 * e20.y + q3 * e30.y;
                a0.z += q0 * e00.z + q1 * e10.z + q2 * e20.z + q3 * e30.z;
                a0.w += q0 * e00.w + q1 * e10.w + q2 * e20.w + q3 * e30.w;
                a1.x += q0 * e01.x + q1 * e11.x + q2 * e21.x + q3 * e31.x;
                a1.y += q0 * e01.y + q1 * e11.y + q2 * e21.y + q3 * e31.y;
                a1.z += q0 * e01.z + q1 * e11.z + q2 * e21.z + q3 * e31.z;
                a1.w += q0 * e01.w + q1 * e11.w + q2 * e21.w + q3 * e31.w;
                a2.x += q0 * e02.x + q1 * e12.x + q2 * e22.x + q3 * e32.x;
                a2.y += q0 * e02.y + q1 * e12.y + q2 * e22.y + q3 * e32.y;
                a2.z += q0 * e02.z + q1 * e12.z + q2 * e22.z + q3 * e32.z;
                a2.w += q0 * e02.w + q1 * e12.w + q2 * e22.w + q3 * e32.w;
                a3.x += q0 * e03.x + q1 * e13.x + q2 * e23.x + q3 * e33.x;
                a3.y += q0 * e03.y + q1 * e13.y + q2 * e23.y + q3 * e33.y;
                a3.z += q0 * e03.z + q1 * e13.z + q2 * e23.z + q3 * e33.z;
                a3.w += q0 * e03.w + q1 * e13.w + q2 * e23.w + q3 * e33.w;
            }
            for (; r < rend; ++r) {  // tail (0..3 rows)
                const float4* ep = (const float4*)(erow + (size_t)r * DD);
                float4 e0 = ep[lane], e1 = ep[lane + 64], e2 = ep[lane + 128], e3 = ep[lane + 192];
                float p0 = dot4(e0, x0) + dot4(e1, x1) + dot4(e2, x2) + dot4(e3, x3);
                p0 = wave_reduce_sum(p0);
                float v0 = (p0 == 0.0f) ? NEG_BIG : p0;
                if (lane == 0) scores[b * SS + srow + r] = v0;
                float mm = fmaxf(m, v0);
                float sc = __expf(m - mm);
                m = mm;
                l *= sc;
                a0.x *= sc; a0.y *= sc; a0.z *= sc; a0.w *= sc;
                a1.x *= sc; a1.y *= sc; a1.z *= sc; a1.w *= sc;
                a2.x *= sc; a2.y *= sc; a2.z *= sc; a2.w *= sc;
                a3.x *= sc; a3.y *= sc; a3.z *= sc; a3.w *= sc;
                float q0 = __expf(v0 - mm);
                l += q0;
                a0.x += q0 * e0.x; a0.y += q0 * e0.y; a0.z += q0 * e0.z; a0.w += q0 * e0.w;
                a1.x += q0 * e1.x; a1.y += q0 * e1.y; a1.z += q0 * e1.z; a1.w += q0 * e1.w;
                a2.x += q0 * e2.x; a2.y += q0 * e2.y; a2.z += q0 * e2.z; a2.w += q0 * e2.w;
                a3.x += q0 * e3.x; a3.y += q0 * e3.y; a3.z += q0 * e3.z; a3.w += q0 * e3.w;
            }
        }
        // rows >= len: untouched; K6 emits attn=0 for them (exp(-1e10-M)==0).

        lctx[w][lane] = a0;
        lctx[w][lane + 64] = a1;
        lctx[w][lane + 128] = a2;
        lctx[w][lane + 192] = a3;
        if (lane == 0) { lm[w] = m; ll[w] = l; }
        __syncthreads();

        if (tid < 256) {
            float M = lm[0];
#pragma unroll
            for (int k = 1; k < 8; ++k) M = fmaxf(M, lm[k]);
            float L = 0.f;
            float4 sum = {0, 0, 0, 0};
#pragma unroll
            for (int k = 0; k < 8; ++k) {
                float sc = __expf(lm[k] - M);  // empty waves contribute 0
                L += sc * ll[k];
                float4 c = lctx[k][tid];
                sum.x += sc * c.x; sum.y += sc * c.y; sum.z += sc * c.z; sum.w += sc * c.w;
            }
            int cc = ((tid >> 6) << 8) | ((tid & 63) << 2);
            *(float4*)(ctxp + ((size_t)(b * NSPLIT + sp)) * DD + cc) = sum;
            if (tid == 0) {
                m_part[b * NSPLIT + sp] = M;
                l_part[b * NSPLIT + sp] = L;
            }
        }
        __syncthreads();  // protect lctx reuse on next chunk
    }
}

// ---------------- K3: combine busy partials -> ctx, Mb, Lb ---- R8-exact ----------------
__global__ __launch_bounds__(256) void k3_combine(const float* __restrict__ ctxp,
                                                  const float* __restrict__ m_part,
                                                  const float* __restrict__ l_part,
                                                  const int* __restrict__ src_lens,
                                                  float* __restrict__ ctx,
                                                  float* __restrict__ Mb,
                                                  float* __restrict__ Lb) {
    int b = blockIdx.x >> 2;
    int col = (blockIdx.x & 3) * 256 + threadIdx.x;
    int nb = (src_lens[b] + 63) >> 6;  // busy chunks for this batch
    float M = NEG_BIG;
    for (int k = 0; k < nb; ++k) M = fmaxf(M, m_part[b * NSPLIT + k]);
    float L = 0.f;
    float sum = 0.f;
    for (int k = 0; k < nb; ++k) {
        float sc = __expf(m_part[b * NSPLIT + k] - M);
        L += sc * l_part[b * NSPLIT + k];
        sum += sc * ctxp[((size_t)(b * NSPLIT + k)) * DD + col];
    }
    ctx[(size_t)b * DD + col] = sum / L;
    if (threadIdx.x == 0 && (blockIdx.x & 3) == 0) { Mb[b] = M; Lb[b] = L; }
}

// ---------------- K5: out_part = cat([ctx,hidden]) @ W2^T (split-K) ---- R8-exact ----------------
__global__ __launch_bounds__(256) void k5_outgemm(const float* __restrict__ ctx,
                                                  const float* __restrict__ hidden,
                                                  const float* __restrict__ W2,
                                                  float* __restrict__ outp) {
    int dt = blockIdx.x & 31;
    int ks = blockIdx.x >> 5;
    int tid = threadIdx.x;
    __shared__ float cat_s[32 * 128];
    __shared__ float w2_s[32 * 128];
    int b0 = tid & 15, b1 = b0 + 16;
    int dl0 = (tid >> 4) * 2, dl1 = dl0 + 1;
    float acc00 = 0.f, acc01 = 0.f, acc10 = 0.f, acc11 = 0.f;

    int j0 = ks * 128;
#pragma unroll
    for (int pass = 0; pass < 4; ++pass) {
        int r = pass * 8 + (tid >> 5);
        int jj4 = tid & 31;
        int j = j0 + jj4 * 4;
        const float* src = (j < 1024) ? (ctx + (size_t)r * 1024 + j)
                                      : (hidden + (size_t)r * 1024 + (j - 1024));
        float4 v = *(const float4*)src;
        *(float4*)(cat_s + r * 128 + ((jj4 ^ (r & 7)) << 2)) = v;
        int dg = dt * 32 + r;
        float4 wv = *(const float4*)(W2 + (size_t)dg * HD + j);
        *(float4*)(w2_s + r * 128 + ((jj4 ^ (r & 7)) << 2)) = wv;
    }
    __syncthreads();
#pragma unroll 4
    for (int jj4 = 0; jj4 < 32; ++jj4) {
        float4 cA = *(const float4*)(cat_s + b0 * 128 + ((jj4 ^ (b0 & 7)) << 2));
        float4 cB = *(const float4*)(cat_s + b1 * 128 + ((jj4 ^ (b1 & 7)) << 2));
        float4 wA = *(const float4*)(w2_s + dl0 * 128 + ((jj4 ^ (dl0 & 7)) << 2));
        float4 wB = *(const float4*)(w2_s + dl1 * 128 + ((jj4 ^ (dl1 & 7)) << 2));
        acc00 += dot4(cA, wA);
        acc01 += dot4(cA, wB);
        acc10 += dot4(cB, wA);
        acc11 += dot4(cB, wB);
    }
    float* op = outp + (size_t)ks * (BB * DD);
    op[b0 * 1024 + dt * 32 + dl0] = acc00;
    op[b0 * 1024 + dt * 32 + dl1] = acc01;
    op[b1 * 1024 + dt * 32 + dl0] = acc10;
    op[b1 * 1024 + dt * 32 + dl1] = acc11;
}

// ---------------- K6: finalize ---- R8-exact ----------------
__global__ __launch_bounds__(256) void k6_final(const float* __restrict__ outp,
                                                const float* __restrict__ scores,
                                                const int* __restrict__ src_lens,
                                                const float* __restrict__ Mb,
                                                const float* __restrict__ Lb,
                                                float* __restrict__ out) {
    int i = blockIdx.x * 256 + threadIdx.x;
    if (i < BB * DD) {
        float s = 0.f;
#pragma unroll
        for (int k = 0; k < KSPLIT; ++k) s += outp[(size_t)k * (BB * DD) + i];
        out[i] = tanhf(s);
    } else {
        int j = i - BB * DD;           // attn.T index: j = s*B + b
        int b = j & 31, sIdx = j >> 5;
        float v = 0.0f;                // rows >= len: exp(-1e10 - M) == 0 exactly
        if (sIdx < src_lens[b]) v = __expf(scores[b * SS + sIdx] - Mb[b]) / Lb[b];
        out[i] = v;
    }
}

extern "C" void kernel_launch(void* const* d_in, const int* in_sizes, int n_in,
                              void* d_out, int out_size, void* d_ws, size_t ws_size,
                              hipStream_t stream) {
    const float* hidden = (const float*)d_in[0];
    const float* enc = (const float*)d_in[1];
    const int* src_lens = (const int*)d_in[2];
    const float* W1 = (const float*)d_in[3];
    const float* W2 = (const float*)d_in[4];
    float* out = (float*)d_out;
    float* ws = (float*)d_ws;

    // ws layout (floats)
    float* x = ws;                       // 32768
    float* scores = ws + 32768;          // 65536
    float* ctxp = ws + 98304;            // 32*32*1024 = 1048576
    float* m_part = ws + 1146880;        // 1024
    float* l_part = ws + 1147904;        // 1024
    float* Mb = ws + 1148928;            // 32
    float* Lb = ws + 1148960;            // 32
    float* ctx = ws + 1148992;           // 32768
    float* outp = ws + 1181760;          // 16*32768 = 524288  (total ~6.8 MB)

    // MEASUREMENT ROUND: K1, K3, K5, K6 each launched twice (all idempotent).
    // dur_us - 57.5 ~= K1 + K3 + K5 + K6 aggregate duration.
    k1_gemv_x<<<256, 256, 0, stream>>>(hidden, W1, x);
    k1_gemv_x<<<256, 256, 0, stream>>>(hidden, W1, x);
    k2_fused<<<512, 512, 0, stream>>>(enc, x, src_lens, scores, ctxp, m_part, l_part);
    k3_combine<<<128, 256, 0, stream>>>(ctxp, m_part, l_part, src_lens, ctx, Mb, Lb);
    k3_combine<<<128, 256, 0, stream>>>(ctxp, m_part, l_part, src_lens, ctx, Mb, Lb);
    k5_outgemm<<<512, 256, 0, stream>>>(ctx, hidden, W2, outp);
    k5_outgemm<<<512, 256, 0, stream>>>(ctx, hidden, W2, outp);
    k6_final<<<384, 256, 0, stream>>>(outp, scores, src_lens, Mb, Lb, out);
    k6_final<<<384, 256, 0, stream>>>(outp, scores, src_lens, Mb, Lb, out);
}

// Round 15
// 54.825 us; speedup vs baseline: 4.9122x; 1.4693x over previous
//
#include <hip/hip_runtime.h>
#include <hip/hip_bf16.h>
#include <math.h>

// Problem constants
#define BB 32
#define SS 2048
#define HH 1024
#define DD 1024
#define HD 2048
#define NSPLIT 32   // 64-row chunks per batch (max)
#define KSPLIT 8    // K-splits for out GEMM (256 cols each)
#define NEG_BIG -1e10f

__device__ __forceinline__ float wave_reduce_sum(float v) {
#pragma unroll
    for (int off = 32; off > 0; off >>= 1) v += __shfl_xor(v, off, 64);
    return v;
}

__device__ __forceinline__ float dot4(float4 a, float4 b) {
    return a.x * b.x + a.y * b.y + a.z * b.z + a.w * b.w;
}

// ---------------- K1: x = hidden @ W1^T  (B x D) ----------------
// grid 512, block 256 (4 waves). Block = (dgroup, bhalf): wave w computes
// d = dgroup*4+w for 16 batches. Chain halved vs R8; 2 blocks/CU.
__global__ __launch_bounds__(256) void k1_gemv_x(const float* __restrict__ hidden,
                                                 const float* __restrict__ W1,
                                                 float* __restrict__ x) {
    __shared__ float4 hs[16 * 256];  // 64 KB: 16 batches of hidden
    int tid = threadIdx.x;
    int w = tid >> 6, lane = tid & 63;
    int d = (blockIdx.x >> 1) * 4 + w;
    int bbase = (blockIdx.x & 1) * 16;
    const float4* wp = (const float4*)(W1 + (size_t)d * HH);
    float4 w0 = wp[lane], w1 = wp[lane + 64], w2 = wp[lane + 128], w3 = wp[lane + 192];
    const float4* hp = (const float4*)(hidden + (size_t)bbase * HH);

#pragma unroll
    for (int i = 0; i < 16; ++i) hs[i * 256 + tid] = hp[i * 256 + tid];
    __syncthreads();
#pragma unroll
    for (int bl = 0; bl < 16; bl += 2) {
        const float4* hb0 = hs + bl * 256;
        const float4* hb1 = hs + (bl + 1) * 256;
        float s0 = dot4(hb0[lane], w0) + dot4(hb0[lane + 64], w1) +
                   dot4(hb0[lane + 128], w2) + dot4(hb0[lane + 192], w3);
        float s1 = dot4(hb1[lane], w0) + dot4(hb1[lane + 64], w1) +
                   dot4(hb1[lane + 128], w2) + dot4(hb1[lane + 192], w3);
#pragma unroll
        for (int off = 32; off > 0; off >>= 1) {
            s0 += __shfl_xor(s0, off, 64);
            s1 += __shfl_xor(s1, off, 64);
        }
        if (lane == 0) {
            x[(bbase + bl) * DD + d] = s0;
            x[(bbase + bl + 1) * DD + d] = s1;
        }
    }
}

// ---------------- K2: fused scores + online-softmax ctx partials ---- R8-exact ----------------
__global__ __launch_bounds__(512) void k2_fused(const float* __restrict__ enc,
                                                const float* __restrict__ x,
                                                const int* __restrict__ src_lens,
                                                float* __restrict__ scores,
                                                float* __restrict__ ctxp,
                                                float* __restrict__ m_part,
                                                float* __restrict__ l_part) {
    int tid = threadIdx.x;
    int w = tid >> 6, lane = tid & 63;

    __shared__ int pfx[BB + 1];
    if (tid == 0) {
        int a = 0;
        pfx[0] = 0;
#pragma unroll
        for (int b = 0; b < BB; ++b) {
            a += (src_lens[b] + 63) >> 6;
            pfx[b + 1] = a;
        }
    }
    __shared__ float4 lctx[8][256];  // 32 KB
    __shared__ float lm[8], ll[8];
    __syncthreads();
    int total = pfx[BB];

    for (int chunk = blockIdx.x; chunk < total; chunk += gridDim.x) {
        int b = 0;
        while (pfx[b + 1] <= chunk) ++b;  // uniform, <=32 iters
        int sp = chunk - pfx[b];
        int len = src_lens[b];
        int srow = sp * 64 + w * 8;

        float m = NEG_BIG, l = 0.f;
        float4 a0 = {0, 0, 0, 0}, a1 = {0, 0, 0, 0}, a2 = {0, 0, 0, 0}, a3 = {0, 0, 0, 0};

        if (srow < len) {
            const float4* xp = (const float4*)(x + (size_t)b * DD);
            float4 x0 = xp[lane], x1 = xp[lane + 64], x2 = xp[lane + 128], x3 = xp[lane + 192];
            int rend = min(8, len - srow);
            const float* erow = enc + ((size_t)b * SS + srow) * DD;
            int r = 0;
            for (; r + 4 <= rend; r += 4) {
                const float4* pr0 = (const float4*)(erow + (size_t)(r + 0) * DD);
                const float4* pr1 = (const float4*)(erow + (size_t)(r + 1) * DD);
                const float4* pr2 = (const float4*)(erow + (size_t)(r + 2) * DD);
                const float4* pr3 = (const float4*)(erow + (size_t)(r + 3) * DD);
                float4 e00 = pr0[lane], e01 = pr0[lane + 64], e02 = pr0[lane + 128], e03 = pr0[lane + 192];
                float4 e10 = pr1[lane], e11 = pr1[lane + 64], e12 = pr1[lane + 128], e13 = pr1[lane + 192];
                float4 e20 = pr2[lane], e21 = pr2[lane + 64], e22 = pr2[lane + 128], e23 = pr2[lane + 192];
                float4 e30 = pr3[lane], e31 = pr3[lane + 64], e32 = pr3[lane + 128], e33 = pr3[lane + 192];
                float p0 = dot4(e00, x0) + dot4(e01, x1) + dot4(e02, x2) + dot4(e03, x3);
                float p1 = dot4(e10, x0) + dot4(e11, x1) + dot4(e12, x2) + dot4(e13, x3);
                float p2 = dot4(e20, x0) + dot4(e21, x1) + dot4(e22, x2) + dot4(e23, x3);
                float p3 = dot4(e30, x0) + dot4(e31, x1) + dot4(e32, x2) + dot4(e33, x3);
#pragma unroll
                for (int off = 32; off > 0; off >>= 1) {  // 4-way interleaved butterflies
                    p0 += __shfl_xor(p0, off, 64);
                    p1 += __shfl_xor(p1, off, 64);
                    p2 += __shfl_xor(p2, off, 64);
                    p3 += __shfl_xor(p3, off, 64);
                }
                float v0 = (p0 == 0.0f) ? NEG_BIG : p0;  // torch quirk
                float v1 = (p1 == 0.0f) ? NEG_BIG : p1;
                float v2 = (p2 == 0.0f) ? NEG_BIG : p2;
                float v3 = (p3 == 0.0f) ? NEG_BIG : p3;
                if (lane == 0) {
                    scores[b * SS + srow + r + 0] = v0;
                    scores[b * SS + srow + r + 1] = v1;
                    scores[b * SS + srow + r + 2] = v2;
                    scores[b * SS + srow + r + 3] = v3;
                }
                float mm = fmaxf(m, fmaxf(fmaxf(v0, v1), fmaxf(v2, v3)));
                float sc = __expf(m - mm);  // == 1.0 when mm == m
                m = mm;
                l *= sc;
                a0.x *= sc; a0.y *= sc; a0.z *= sc; a0.w *= sc;
                a1.x *= sc; a1.y *= sc; a1.z *= sc; a1.w *= sc;
                a2.x *= sc; a2.y *= sc; a2.z *= sc; a2.w *= sc;
                a3.x *= sc; a3.y *= sc; a3.z *= sc; a3.w *= sc;
                float q0 = __expf(v0 - mm), q1 = __expf(v1 - mm);
                float q2 = __expf(v2 - mm), q3 = __expf(v3 - mm);
                l += q0 + q1 + q2 + q3;
                a0.x += q0 * e00.x + q1 * e10.x + q2 * e20.x + q3 * e30.x;
                a0.y += q0 * e00.y + q1 * e10.y + q2 * e20.y + q3 * e30.y;
                a0.z += q0 * e00.z + q1 * e10.z + q2 * e20.z + q3 * e30.z;
                a0.w += q0 * e00.w + q1 * e10.w + q2 * e20.w + q3 * e30.w;
                a1.x += q0 * e01.x + q1 * e11.x + q2 * e21.x + q3 * e31.x;
                a1.y += q0 * e01.y + q1 * e11.y + q2 * e21.y + q3 * e31.y;
                a1.z += q0 * e01.z + q1 * e11.z + q2 * e21.z + q3 * e31.z;
                a1.w += q0 * e01.w + q1 * e11.w + q2 * e21.w + q3 * e31.w;
                a2.x += q0 * e02.x + q1 * e12.x + q2 * e22.x + q3 * e32.x;
                a2.y += q0 * e02.y + q1 * e12.y + q2 * e22.y + q3 * e32.y;
                a2.z += q0 * e02.z + q1 * e12.z + q2 * e22.z + q3 * e32.z;
                a2.w += q0 * e02.w + q1 * e12.w + q2 * e22.w + q3 * e32.w;
                a3.x += q0 * e03.x + q1 * e13.x + q2 * e23.x + q3 * e33.x;
                a3.y += q0 * e03.y + q1 * e13.y + q2 * e23.y + q3 * e33.y;
                a3.z += q0 * e03.z + q1 * e13.z + q2 * e23.z + q3 * e33.z;
                a3.w += q0 * e03.w + q1 * e13.w + q2 * e23.w + q3 * e33.w;
            }
            for (; r < rend; ++r) {  // tail (0..3 rows)
                const float4* ep = (const float4*)(erow + (size_t)r * DD);
                float4 e0 = ep[lane], e1 = ep[lane + 64], e2 = ep[lane + 128], e3 = ep[lane + 192];
                float p0 = dot4(e0, x0) + dot4(e1, x1) + dot4(e2, x2) + dot4(e3, x3);
                p0 = wave_reduce_sum(p0);
                float v0 = (p0 == 0.0f) ? NEG_BIG : p0;
                if (lane == 0) scores[b * SS + srow + r] = v0;
                float mm = fmaxf(m, v0);
                float sc = __expf(m - mm);
                m = mm;
                l *= sc;
                a0.x *= sc; a0.y *= sc; a0.z *= sc; a0.w *= sc;
                a1.x *= sc; a1.y *= sc; a1.z *= sc; a1.w *= sc;
                a2.x *= sc; a2.y *= sc; a2.z *= sc; a2.w *= sc;
                a3.x *= sc; a3.y *= sc; a3.z *= sc; a3.w *= sc;
                float q0 = __expf(v0 - mm);
                l += q0;
                a0.x += q0 * e0.x; a0.y += q0 * e0.y; a0.z += q0 * e0.z; a0.w += q0 * e0.w;
                a1.x += q0 * e1.x; a1.y += q0 * e1.y; a1.z += q0 * e1.z; a1.w += q0 * e1.w;
                a2.x += q0 * e2.x; a2.y += q0 * e2.y; a2.z += q0 * e2.z; a2.w += q0 * e2.w;
                a3.x += q0 * e3.x; a3.y += q0 * e3.y; a3.z += q0 * e3.z; a3.w += q0 * e3.w;
            }
        }
        // rows >= len: untouched; K6 emits attn=0 for them (exp(-1e10-M)==0).

        lctx[w][lane] = a0;
        lctx[w][lane + 64] = a1;
        lctx[w][lane + 128] = a2;
        lctx[w][lane + 192] = a3;
        if (lane == 0) { lm[w] = m; ll[w] = l; }
        __syncthreads();

        if (tid < 256) {
            float M = lm[0];
#pragma unroll
            for (int k = 1; k < 8; ++k) M = fmaxf(M, lm[k]);
            float L = 0.f;
            float4 sum = {0, 0, 0, 0};
#pragma unroll
            for (int k = 0; k < 8; ++k) {
                float sc = __expf(lm[k] - M);  // empty waves contribute 0
                L += sc * ll[k];
                float4 c = lctx[k][tid];
                sum.x += sc * c.x; sum.y += sc * c.y; sum.z += sc * c.z; sum.w += sc * c.w;
            }
            int cc = ((tid >> 6) << 8) | ((tid & 63) << 2);
            *(float4*)(ctxp + ((size_t)(b * NSPLIT + sp)) * DD + cc) = sum;
            if (tid == 0) {
                m_part[b * NSPLIT + sp] = M;
                l_part[b * NSPLIT + sp] = L;
            }
        }
        __syncthreads();  // protect lctx reuse on next chunk
    }
}

// ---------------- K3: combine busy partials -> ctx, Mb, Lb ---- R8-exact ----------------
__global__ __launch_bounds__(256) void k3_combine(const float* __restrict__ ctxp,
                                                  const float* __restrict__ m_part,
                                                  const float* __restrict__ l_part,
                                                  const int* __restrict__ src_lens,
                                                  float* __restrict__ ctx,
                                                  float* __restrict__ Mb,
                                                  float* __restrict__ Lb) {
    int b = blockIdx.x >> 2;
    int col = (blockIdx.x & 3) * 256 + threadIdx.x;
    int nb = (src_lens[b] + 63) >> 6;  // busy chunks for this batch
    float M = NEG_BIG;
    for (int k = 0; k < nb; ++k) M = fmaxf(M, m_part[b * NSPLIT + k]);
    float L = 0.f;
    float sum = 0.f;
    for (int k = 0; k < nb; ++k) {
        float sc = __expf(m_part[b * NSPLIT + k] - M);
        L += sc * l_part[b * NSPLIT + k];
        sum += sc * ctxp[((size_t)(b * NSPLIT + k)) * DD + col];
    }
    ctx[(size_t)b * DD + col] = sum / L;
    if (threadIdx.x == 0 && (blockIdx.x & 3) == 0) { Mb[b] = M; Lb[b] = L; }
}

// ---------------- K5: out_part = cat([ctx,hidden]) @ W2^T (split-K 8x256) ----------------
// grid 256 = 32 dtiles * 8 ksplits, block 256. Single 256-col stage (no loop);
// per-block cat source is uniform (256-col chunks don't straddle the seam).
__global__ __launch_bounds__(256) void k5_outgemm(const float* __restrict__ ctx,
                                                  const float* __restrict__ hidden,
                                                  const float* __restrict__ W2,
                                                  float* __restrict__ outp) {
    int dt = blockIdx.x & 31;
    int ks = blockIdx.x >> 5;  // 0..7
    int tid = threadIdx.x;
    __shared__ float cat_s[32 * 256];  // 32 KB
    __shared__ float w2_s[32 * 256];   // 32 KB
    int b0 = tid & 15, b1 = b0 + 16;
    int dl0 = (tid >> 4) * 2, dl1 = dl0 + 1;
    float acc00 = 0.f, acc01 = 0.f, acc10 = 0.f, acc11 = 0.f;

    int j0 = ks * 256;
    const float* cbase = (j0 < 1024) ? (ctx + j0) : (hidden + (j0 - 1024));
#pragma unroll
    for (int pass = 0; pass < 8; ++pass) {
        int idx = pass * 256 + tid;  // 0..2047
        int r = idx >> 6;            // row 0..31
        int s = idx & 63;            // float4 slot 0..63
        float4 v = *(const float4*)(cbase + (size_t)r * 1024 + s * 4);
        *(float4*)(cat_s + r * 256 + ((s ^ (r & 7)) << 2)) = v;
        int dg = dt * 32 + r;
        float4 wv = *(const float4*)(W2 + (size_t)dg * HD + j0 + s * 4);
        *(float4*)(w2_s + r * 256 + ((s ^ (r & 7)) << 2)) = wv;
    }
    __syncthreads();
#pragma unroll 4
    for (int s = 0; s < 64; ++s) {
        float4 cA = *(const float4*)(cat_s + b0 * 256 + ((s ^ (b0 & 7)) << 2));
        float4 cB = *(const float4*)(cat_s + b1 * 256 + ((s ^ (b1 & 7)) << 2));
        float4 wA = *(const float4*)(w2_s + dl0 * 256 + ((s ^ (dl0 & 7)) << 2));
        float4 wB = *(const float4*)(w2_s + dl1 * 256 + ((s ^ (dl1 & 7)) << 2));
        acc00 += dot4(cA, wA);
        acc01 += dot4(cA, wB);
        acc10 += dot4(cB, wA);
        acc11 += dot4(cB, wB);
    }
    float* op = outp + (size_t)ks * (BB * DD);
    op[b0 * 1024 + dt * 32 + dl0] = acc00;
    op[b0 * 1024 + dt * 32 + dl1] = acc01;
    op[b1 * 1024 + dt * 32 + dl0] = acc10;
    op[b1 * 1024 + dt * 32 + dl1] = acc11;
}

// ---------------- K6: finalize: out = tanh(sum partials); attn.T ----------------
__global__ __launch_bounds__(256) void k6_final(const float* __restrict__ outp,
                                                const float* __restrict__ scores,
                                                const int* __restrict__ src_lens,
                                                const float* __restrict__ Mb,
                                                const float* __restrict__ Lb,
                                                float* __restrict__ out) {
    int i = blockIdx.x * 256 + threadIdx.x;
    if (i < BB * DD) {
        float s = 0.f;
#pragma unroll
        for (int k = 0; k < KSPLIT; ++k) s += outp[(size_t)k * (BB * DD) + i];
        out[i] = tanhf(s);
    } else {
        int j = i - BB * DD;           // attn.T index: j = s*B + b
        int b = j & 31, sIdx = j >> 5;
        float v = 0.0f;                // rows >= len: exp(-1e10 - M) == 0 exactly
        if (sIdx < src_lens[b]) v = __expf(scores[b * SS + sIdx] - Mb[b]) / Lb[b];
        out[i] = v;
    }
}

extern "C" void kernel_launch(void* const* d_in, const int* in_sizes, int n_in,
                              void* d_out, int out_size, void* d_ws, size_t ws_size,
                              hipStream_t stream) {
    const float* hidden = (const float*)d_in[0];
    const float* enc = (const float*)d_in[1];
    const int* src_lens = (const int*)d_in[2];
    const float* W1 = (const float*)d_in[3];
    const float* W2 = (const float*)d_in[4];
    float* out = (float*)d_out;
    float* ws = (float*)d_ws;

    // ws layout (floats)
    float* x = ws;                       // 32768
    float* scores = ws + 32768;          // 65536
    float* ctxp = ws + 98304;            // 32*32*1024 = 1048576
    float* m_part = ws + 1146880;        // 1024
    float* l_part = ws + 1147904;        // 1024
    float* Mb = ws + 1148928;            // 32
    float* Lb = ws + 1148960;            // 32
    float* ctx = ws + 1148992;           // 32768
    float* outp = ws + 1181760;          // 8*32768 = 262144  (total ~5.8 MB)

    k1_gemv_x<<<512, 256, 0, stream>>>(hidden, W1, x);
    k2_fused<<<512, 512, 0, stream>>>(enc, x, src_lens, scores, ctxp, m_part, l_part);
    k3_combine<<<128, 256, 0, stream>>>(ctxp, m_part, l_part, src_lens, ctx, Mb, Lb);
    k5_outgemm<<<256, 256, 0, stream>>>(ctx, hidden, W2, outp);
    k6_final<<<384, 256, 0, stream>>>(outp, scores, src_lens, Mb, Lb, out);
}